// Round 1
// baseline (124.806 us; speedup 1.0000x reference)
//
#include <hip/hip_runtime.h>

// Problem shape (fixed by the reference): data/mask [B,T,D] float32.
#define BB 8
#define TT 4096
#define DD 1024
#define LL 64            // chunk length along T
#define CC (TT / LL)     // 64 chunks
#define D4 (DD / 4)      // 256 float4 columns

// ---------------------------------------------------------------------------
// Phase 1: per (b, chunk, d4) find the LAST valid value in the chunk.
// Backward scan with early exit (expected ~1.2 iterations at 10% missing).
// carry layout: 2 float4 per thread-id: (v0,f0,v1,f1) (v2,f2,v3,f3)
// ---------------------------------------------------------------------------
__global__ __launch_bounds__(256) void ff_chunk_carry(
    const float4* __restrict__ data, const float4* __restrict__ mask,
    float4* __restrict__ carry) {
  int tid = blockIdx.x * blockDim.x + threadIdx.x;
  if (tid >= BB * CC * D4) return;
  int d4 = tid & (D4 - 1);
  int bc = tid / D4;  // b*CC + c ; row offset (b*TT + c*LL) == bc*LL

  float vx = 0.f, vy = 0.f, vz = 0.f, vw = 0.f;
  int found = 0;
  long base = ((long)bc * LL + (LL - 1)) * D4 + d4;
  for (int i = LL - 1; i >= 0 && found != 0xF; --i, base -= D4) {
    float4 m = mask[base];
    float4 v = data[base];
    if (!(found & 1) && m.x > 0.f) { vx = v.x; found |= 1; }
    if (!(found & 2) && m.y > 0.f) { vy = v.y; found |= 2; }
    if (!(found & 4) && m.z > 0.f) { vz = v.z; found |= 4; }
    if (!(found & 8) && m.w > 0.f) { vw = v.w; found |= 8; }
  }
  float4* out = carry + (long)tid * 2;
  out[0] = make_float4(vx, (found & 1) ? 1.f : 0.f, vy, (found & 2) ? 1.f : 0.f);
  out[1] = make_float4(vz, (found & 4) ? 1.f : 0.f, vw, (found & 8) ? 1.f : 0.f);
}

// ---------------------------------------------------------------------------
// Phase 2: exclusive prefix over chunks for each (b, d4). "No valid yet" is
// representable as 0.0f == FILL_VALUE, so carry-in needs no flag.
// ---------------------------------------------------------------------------
__global__ __launch_bounds__(256) void ff_scan_carry(
    const float4* __restrict__ carry, float4* __restrict__ cin) {
  int tid = blockIdx.x * blockDim.x + threadIdx.x;  // b*D4 + d4
  if (tid >= BB * D4) return;
  int d4 = tid & (D4 - 1);
  int b = tid / D4;

  float4 cur = make_float4(0.f, 0.f, 0.f, 0.f);
  for (int c = 0; c < CC; ++c) {
    long k = (long)(b * CC + c) * D4 + d4;
    float4 a0 = carry[k * 2];
    float4 a1 = carry[k * 2 + 1];
    cin[k] = cur;
    if (a0.y > 0.f) cur.x = a0.x;
    if (a0.w > 0.f) cur.y = a0.z;
    if (a1.y > 0.f) cur.z = a1.x;
    if (a1.w > 0.f) cur.w = a1.z;
  }
}

// ---------------------------------------------------------------------------
// Phase 3 (dominant): forward fill within each chunk starting from carry-in.
// Fully coalesced float4 loads/stores; mask pass-through fused (output 1).
// ---------------------------------------------------------------------------
__global__ __launch_bounds__(256) void ff_apply(
    const float4* __restrict__ data, const float4* __restrict__ mask,
    const float4* __restrict__ cin, float4* __restrict__ outf,
    float4* __restrict__ outm) {
  int tid = blockIdx.x * blockDim.x + threadIdx.x;
  if (tid >= BB * CC * D4) return;
  int d4 = tid & (D4 - 1);
  int bc = tid / D4;

  float4 last = cin[tid];
  long base = (long)bc * LL * D4 + d4;
#pragma unroll 4
  for (int i = 0; i < LL; ++i, base += D4) {
    float4 m = mask[base];
    float4 v = data[base];
    last.x = (m.x > 0.f) ? v.x : last.x;
    last.y = (m.y > 0.f) ? v.y : last.y;
    last.z = (m.z > 0.f) ? v.z : last.z;
    last.w = (m.w > 0.f) ? v.w : last.w;
    outf[base] = last;
    outm[base] = m;
  }
}

// ---------------------------------------------------------------------------
// Fallback (only if workspace is too small): one thread per (b, d4) scans the
// whole column. Correct but low-parallelism.
// ---------------------------------------------------------------------------
__global__ __launch_bounds__(256) void ff_naive(
    const float4* __restrict__ data, const float4* __restrict__ mask,
    float4* __restrict__ outf, float4* __restrict__ outm) {
  int tid = blockIdx.x * blockDim.x + threadIdx.x;
  if (tid >= BB * D4) return;
  int d4 = tid & (D4 - 1);
  int b = tid / D4;

  float4 last = make_float4(0.f, 0.f, 0.f, 0.f);
  long base = (long)b * TT * D4 + d4;
  for (int t = 0; t < TT; ++t, base += D4) {
    float4 m = mask[base];
    float4 v = data[base];
    last.x = (m.x > 0.f) ? v.x : last.x;
    last.y = (m.y > 0.f) ? v.y : last.y;
    last.z = (m.z > 0.f) ? v.z : last.z;
    last.w = (m.w > 0.f) ? v.w : last.w;
    outf[base] = last;
    outm[base] = m;
  }
}

extern "C" void kernel_launch(void* const* d_in, const int* in_sizes, int n_in,
                              void* d_out, int out_size, void* d_ws, size_t ws_size,
                              hipStream_t stream) {
  const float4* data = (const float4*)d_in[0];
  const float4* mask = (const float4*)d_in[1];
  const long N = (long)BB * TT * DD;  // elements per output tensor
  float4* outf = (float4*)d_out;
  float4* outm = (float4*)((float*)d_out + N);

  const size_t carry_f4 = (size_t)BB * CC * D4 * 2;  // float4 count
  const size_t cin_f4 = (size_t)BB * CC * D4;
  const size_t need = (carry_f4 + cin_f4) * sizeof(float4);  // 6 MiB

  if (ws_size >= need) {
    float4* carry = (float4*)d_ws;
    float4* cin = carry + carry_f4;
    const int n13 = BB * CC * D4;  // 131072
    ff_chunk_carry<<<n13 / 256, 256, 0, stream>>>(data, mask, carry);
    ff_scan_carry<<<(BB * D4) / 256, 256, 0, stream>>>(carry, cin);
    ff_apply<<<n13 / 256, 256, 0, stream>>>(data, mask, cin, outf, outm);
  } else {
    ff_naive<<<(BB * D4 + 255) / 256, 256, 0, stream>>>(data, mask, outf, outm);
  }
}